// Round 20
// baseline (60.377 us; speedup 1.0000x reference)
//
#include <hip/hip_runtime.h>
#include <hip/hip_bf16.h>
#include <hip/hip_fp16.h>

#define NTOK 2048
#define HEADS 8
#define DHEAD 32
#define CDIM 256
#define BATCH 4

typedef _Float16 f16x8 __attribute__((ext_vector_type(8)));
typedef _Float16 f16x4 __attribute__((ext_vector_type(4)));
typedef float f32x4 __attribute__((ext_vector_type(4)));
typedef __fp16 fp16v2 __attribute__((ext_vector_type(2)));

static __device__ inline f16x4 pack4(float a, float b, float c, float d) {
    fp16v2 lo = __builtin_amdgcn_cvt_pkrtz(a, b);
    fp16v2 hi = __builtin_amdgcn_cvt_pkrtz(c, d);
    union { struct { fp16v2 lo, hi; } p; f16x4 v; } u;
    u.p.lo = lo; u.p.hi = hi;
    return u.v;
}

static __device__ inline f16x8 pack8f(float a, float b, float c, float d,
                                      float e, float f, float g2, float h2) {
    union { struct { fp16v2 a, b, c, d; } p; f16x8 v; } u;
    u.p.a = __builtin_amdgcn_cvt_pkrtz(a, b);
    u.p.b = __builtin_amdgcn_cvt_pkrtz(c, d);
    u.p.c = __builtin_amdgcn_cvt_pkrtz(e, f);
    u.p.d = __builtin_amdgcn_cvt_pkrtz(g2, h2);
    return u.v;
}

static __device__ inline f16x8 pack8(float4 a, float4 b) {
    return pack8f(a.x, a.y, a.z, a.w, b.x, b.y, b.z, b.w);
}

// ---------------------------------------------------------------------------
// Kernel 0: prep — write ALL GEMM operands in MFMA-FRAGMENT-LINEAR order
// buf[tile][kt][lane][8] so every A/B fragment load downstream is
// base + lane*16B (ideal coalescing, zero address divergence).
// ---------------------------------------------------------------------------
__global__ __launch_bounds__(256) void prep(const float* __restrict__ x,
                                            const float* __restrict__ w_qkv,
                                            const float* __restrict__ w_out,
                                            _Float16* __restrict__ xh,
                                            _Float16* __restrict__ wqkvT,
                                            _Float16* __restrict__ woutT) {
    __shared__ float tl[32][33];
    const int bid = blockIdx.x;
    if (bid < 1024) {
        // x -> xh_frag: 262144 chunks of 8
        const int id = bid * 256 + threadIdx.x;
        const int row = id >> 5;
        const int c = id & 31;
        const int kt = c >> 2;
        const int g = c & 3;
        const float4 a = *(const float4*)(x + row * 256 + kt * 32 + g * 8);
        const float4 b = *(const float4*)(x + row * 256 + kt * 32 + g * 8 + 4);
        const int dst = (row >> 4) * 4096 + kt * 512 + (g * 16 + (row & 15)) * 8;
        *(f16x8*)(xh + dst) = pack8(a, b);
    } else if (bid < 1216) {
        // w_qkv[256k][768n] -> wqkvT_frag, 32x32 tiles: 8 kt x 24 nt
        const int t = bid - 1024;
        const int kt = t / 24, nt = t - kt * 24;
        const int tx = threadIdx.x & 31, ty = threadIdx.x >> 5;
#pragma unroll
        for (int i = 0; i < 4; ++i) {
            const int r = ty + i * 8;
            tl[r][tx] = w_qkv[(kt * 32 + r) * 768 + nt * 32 + tx];
        }
        __syncthreads();
        if (threadIdx.x < 128) {
            const int nl = threadIdx.x & 31;
            const int g2 = threadIdx.x >> 5;
            const int ntile = (nt * 32 + nl) >> 4;
            const int lane = (nl & 15) + 16 * g2;
            const float* col = &tl[g2 * 8][nl];
            *(f16x8*)(wqkvT + (ntile * 8 + kt) * 512 + lane * 8) =
                pack8f(col[0], col[33], col[66], col[99],
                       col[132], col[165], col[198], col[231]);
        }
    } else {
        // w_out[256k][256n] -> woutT_frag, 8 kt x 8 nt
        const int t = bid - 1216;
        const int kt = t >> 3, nt = t & 7;
        const int tx = threadIdx.x & 31, ty = threadIdx.x >> 5;
#pragma unroll
        for (int i = 0; i < 4; ++i) {
            const int r = ty + i * 8;
            tl[r][tx] = w_out[(kt * 32 + r) * 256 + nt * 32 + tx];
        }
        __syncthreads();
        if (threadIdx.x < 128) {
            const int nl = threadIdx.x & 31;
            const int g2 = threadIdx.x >> 5;
            const int ntile = (nt * 32 + nl) >> 4;
            const int lane = (nl & 15) + 16 * g2;
            const float* col = &tl[g2 * 8][nl];
            *(f16x8*)(woutT + (ntile * 8 + kt) * 512 + lane * 8) =
                pack8f(col[0], col[33], col[66], col[99],
                       col[132], col[165], col[198], col[231]);
        }
    }
}

// ---------------------------------------------------------------------------
// Kernel 1: QKV GEMM, fragment-linear operands (1KB/wave contiguous loads).
// vT keys PERMUTED within each 32-key block so attn's S^T registers form a
// valid 16x16x32 B-fragment.
// ---------------------------------------------------------------------------
__global__ __launch_bounds__(256) void qkv_gemm(const _Float16* __restrict__ xh,
                                                const _Float16* __restrict__ wT,
                                                _Float16* __restrict__ qb,
                                                _Float16* __restrict__ kb,
                                                _Float16* __restrict__ vT) {
    __shared__ _Float16 vt_s[64 * 72];  // 64 rows x 72 f16 (144B rows)
    const int wave = threadIdx.x >> 6;
    const int lane = threadIdx.x & 63;
    const int idx16 = lane & 15;
    const int g = lane >> 4;

    const int m_base = blockIdx.x * 64;          // 128 m-blocks
    const int n0 = blockIdx.y * 64 + wave * 16;  // 12 n-blocks * 4 waves

    f32x4 acc[4] = {{0.f, 0.f, 0.f, 0.f}, {0.f, 0.f, 0.f, 0.f},
                    {0.f, 0.f, 0.f, 0.f}, {0.f, 0.f, 0.f, 0.f}};

    const _Float16* bp = wT + (size_t)(blockIdx.y * 4 + wave) * 4096 + lane * 8;
    const _Float16* ap = xh + (size_t)(blockIdx.x * 4) * 4096 + lane * 8;

    for (int kt = 0; kt < 8; ++kt) {
        const f16x8 bf = *(const f16x8*)(bp + kt * 512);
#pragma unroll
        for (int m = 0; m < 4; ++m) {
            const f16x8 af = *(const f16x8*)(ap + m * 4096 + kt * 512);
            acc[m] = __builtin_amdgcn_mfma_f32_16x16x32_f16(af, bf, acc[m], 0, 0, 0);
        }
    }

    const int b = m_base >> 11;
    const int nb = m_base & 2047;
    if (blockIdx.y < 8) {
        const int c = n0 + idx16;
        const int which = c >> 8;
        const int h = (c >> 5) & 7;
        const int d = c & 31;
#pragma unroll
        for (int m = 0; m < 4; ++m) {
#pragma unroll
            for (int r = 0; r < 4; ++r) {
                const int n = nb + m * 16 + g * 4 + r;
                const float val = acc[m][r];
                if (which == 0) {
                    qb[((b * HEADS + h) * NTOK + n) * DHEAD + d] =
                        (_Float16)(val * 0.2550565444545147f);  // d^-.5 * log2e
                } else {
                    kb[((b * HEADS + h) * NTOK + n) * DHEAD + d] = (_Float16)val;
                }
            }
        }
    } else {
        const int cp = wave * 16 + idx16;
#pragma unroll
        for (int m = 0; m < 4; ++m) {
            const int kl = m * 16 + g * 4;  // source key within 64-slab
            const int dst = (kl & 32) + (((kl >> 2) & 3) << 3) +
                            (((kl >> 4) & 1) << 2);
            *(f16x4*)(vt_s + cp * 72 + dst) =
                pack4(acc[m][0], acc[m][1], acc[m][2], acc[m][3]);
        }
        __syncthreads();
        const int cpo = threadIdx.x >> 2;
        const int part = threadIdx.x & 3;
        const int vidx = (blockIdx.y - 8) * 64 + cpo;  // 0..255 = h*32+d
        const int hh = vidx >> 5;
        const int d = vidx & 31;
        const _Float16* src = vt_s + cpo * 72 + part * 16;
        _Float16* dst = vT + ((size_t)(b * HEADS + hh) * DHEAD + d) * NTOK +
                        nb + part * 16;
        *(f16x8*)(dst) = *(const f16x8*)(src);
        *(f16x8*)(dst + 8) = *(const f16x8*)(src + 8);
    }
}

// ---------------------------------------------------------------------------
// Kernel 2: flash attention partials, K-split 2 (proven loop, r15/r19).
// r20 NEW EPILOGUE: per-wave 4KB LDS d-transpose (XOR-swizzled 8B units,
// proven in r18) writes UNNORMALIZED out_gemm A-FRAGMENTS
// paccF[ks][tile][kt=h][lane][8] (coalesced f16x8 stores) + pl row sums.
// ---------------------------------------------------------------------------
__global__ __launch_bounds__(256, 4) void attn_partial(
    const _Float16* __restrict__ qp, const _Float16* __restrict__ kp,
    const _Float16* __restrict__ vT, const float* __restrict__ bias_table,
    _Float16* __restrict__ paccF, float* __restrict__ pl) {
    __shared__ float ft[4096];      // quad table: ft[4w+j] = F[w+j]
    __shared__ f16x8 sbuf_v[1024];  // 2 bufs x 8KB (2 tiles x [K 2KB | V 2KB])
    char* sbuf = (char*)sbuf_v;

    const int bh = blockIdx.x;
    const int h = bh & 7;
    for (int u = threadIdx.x; u < 1024; u += 256) {
        const float v =
            bias_table[(1023 - u) * HEADS + h] * 1.4426950408889634f - 8.0f;
        ft[4 * u] = v;
        if (u >= 1) ft[4 * u - 3] = v;
        if (u >= 2) ft[4 * u - 6] = v;
        if (u >= 3) ft[4 * u - 9] = v;
    }

    const int wave = threadIdx.x >> 6;
    const int lane = threadIdx.x & 63;
    const int qi = lane & 15;
    const int g = lane >> 4;
    const int q0 = blockIdx.y * 256 + wave * 64;  // 8 y-blocks, 64 rows/wave
    const int ks = blockIdx.z;
    const int kstart = ks * 1024;

    // ---- staging map: threads 0-127 -> K tile, 128-255 -> V tile ----
    const int tid = threadIdx.x;
    const bool isK = tid < 128;
    const int st_row = (tid & 127) >> 2;
    const int st_c16 = tid & 3;
    const int st_dst = (isK ? 0 : 2048) + st_row * 64 +
                       ((st_c16 ^ ((st_row >> 1) & 3)) << 4);
    const _Float16* st_src = isK
        ? kp + ((size_t)bh * NTOK + kstart + st_row) * DHEAD + st_c16 * 8
        : vT + ((size_t)bh * DHEAD + st_row) * NTOK + kstart + st_c16 * 8;
    const int st_stride = isK ? 32 * DHEAD : 32;  // f16 elems per 32-key tile

    // ---- per-lane LDS read offsets (within a 4KB tile), swizzled ----
    const int swz = (qi >> 1) & 3;
    const int kf0_off = qi * 64 + ((g ^ swz) << 4);
    const int kf1_off = kf0_off + 1024;
    const int va_lo_off = 2048 + qi * 64 + ((g ^ swz) << 4);  // V rows 0-15
    const int va_hi_off = va_lo_off + 1024;                   // V rows 16-31

    // ub[m] = ub0 - m exactly (q0 multiple of 64 -> no nibble wrap, m<4)
    const int ig0 = q0 + qi;
    const int ib0 = 31 * (ig0 >> 8) + ((ig0 >> 4) & 15) + (ig0 & 15) + 704;
    const int ub0 = 1023 - ib0 + 4 * g;

    f16x8 qf[4];
#pragma unroll
    for (int m = 0; m < 4; ++m)
        qf[m] = *(const f16x8*)(qp + (bh * NTOK + q0 + m * 16 + qi) * DHEAD + g * 8);

    f32x4 acc0[4] = {{0.f, 0.f, 0.f, 0.f}, {0.f, 0.f, 0.f, 0.f},
                     {0.f, 0.f, 0.f, 0.f}, {0.f, 0.f, 0.f, 0.f}};
    f32x4 acc1[4] = {{0.f, 0.f, 0.f, 0.f}, {0.f, 0.f, 0.f, 0.f},
                     {0.f, 0.f, 0.f, 0.f}, {0.f, 0.f, 0.f, 0.f}};
    f32x4 accl[4] = {{0.f, 0.f, 0.f, 0.f}, {0.f, 0.f, 0.f, 0.f},
                     {0.f, 0.f, 0.f, 0.f}, {0.f, 0.f, 0.f, 0.f}};
    const f16x8 ones8 = {(_Float16)1.f, (_Float16)1.f, (_Float16)1.f,
                         (_Float16)1.f, (_Float16)1.f, (_Float16)1.f,
                         (_Float16)1.f, (_Float16)1.f};

    // prologue: stage tiles 0,1 into buf 0 (barrier also covers ft fill)
    f16x8 stg0 = *(const f16x8*)(st_src);
    f16x8 stg1 = *(const f16x8*)(st_src + st_stride);
    *(f16x8*)(sbuf + st_dst) = stg0;
    *(f16x8*)(sbuf + 4096 + st_dst) = stg1;
    __syncthreads();

    int cur = 0;
    for (int kt2 = 0; kt2 < 16; ++kt2) {
        // T14: issue next pair's global loads first (hide under compute)
        if (kt2 < 15) {
            stg0 = *(const f16x8*)(st_src + (2 * kt2 + 2) * st_stride);
            stg1 = *(const f16x8*)(st_src + (2 * kt2 + 3) * st_stride);
        }

#pragma unroll
        for (int tp = 0; tp < 2; ++tp) {
            const int kbase = kstart + (kt2 * 2 + tp) * 32;
            const char* bs = sbuf + cur * 8192 + tp * 4096;
            const f16x8 kf0 = *(const f16x8*)(bs + kf0_off);
            const f16x8 kf1 = *(const f16x8*)(bs + kf1_off);
            const f16x8 va_lo = *(const f16x8*)(bs + va_lo_off);
            const f16x8 va_hi = *(const f16x8*)(bs + va_hi_off);

            const int koff = 31 * (kbase >> 8) + ((kbase >> 4) & 15);
            const int u0 = ub0 + koff;

            __builtin_amdgcn_s_setprio(1);
#pragma unroll
            for (int m = 0; m < 4; ++m) {
                const f32x4 c0 = *(const f32x4*)&ft[(u0 - m) << 2];
                const f32x4 c1 = *(const f32x4*)&ft[(u0 - m + 1) << 2];
                f32x4 s0 = __builtin_amdgcn_mfma_f32_16x16x32_f16(kf0, qf[m], c0, 0, 0, 0);
                f32x4 s1 = __builtin_amdgcn_mfma_f32_16x16x32_f16(kf1, qf[m], c1, 0, 0, 0);

                const float p0 = __builtin_amdgcn_exp2f(s0[0]);
                const float p1 = __builtin_amdgcn_exp2f(s0[1]);
                const float p2 = __builtin_amdgcn_exp2f(s0[2]);
                const float p3 = __builtin_amdgcn_exp2f(s0[3]);
                const float p4 = __builtin_amdgcn_exp2f(s1[0]);
                const float p5 = __builtin_amdgcn_exp2f(s1[1]);
                const float p6 = __builtin_amdgcn_exp2f(s1[2]);
                const float p7 = __builtin_amdgcn_exp2f(s1[3]);

                const f16x8 pf = pack8f(p0, p1, p2, p3, p4, p5, p6, p7);

                acc0[m] = __builtin_amdgcn_mfma_f32_16x16x32_f16(va_lo, pf, acc0[m], 0, 0, 0);
                acc1[m] = __builtin_amdgcn_mfma_f32_16x16x32_f16(va_hi, pf, acc1[m], 0, 0, 0);
                accl[m] = __builtin_amdgcn_mfma_f32_16x16x32_f16(ones8, pf, accl[m], 0, 0, 0);
            }
            __builtin_amdgcn_s_setprio(0);
        }

        if (kt2 < 15) {
            *(f16x8*)(sbuf + (cur ^ 1) * 8192 + st_dst) = stg0;
            *(f16x8*)(sbuf + (cur ^ 1) * 8192 + 4096 + st_dst) = stg1;
        }
        __syncthreads();
        cur ^= 1;
    }

    // ---- epilogue: per-wave LDS d-transpose -> UNNORMALIZED A-fragments ----
    // (last loop barrier guarantees sbuf free; regions disjoint per wave)
    const int part = bh * 2 + ks;
    char* ts = sbuf + wave * 4096;  // 64 rows x 64B (32 f16), XOR-swz 8B units
#pragma unroll
    for (int m = 0; m < 4; ++m) {
        const int row = m * 16 + qi;
        const int sw = row & 7;
        *(f16x4*)(ts + row * 64 + ((g ^ sw) << 3)) =
            pack4(acc0[m][0], acc0[m][1], acc0[m][2], acc0[m][3]);
        *(f16x4*)(ts + row * 64 + (((g + 4) ^ sw) << 3)) =
            pack4(acc1[m][0], acc1[m][1], acc1[m][2], acc1[m][3]);
        if (g == 0) pl[part * NTOK + q0 + row] = accl[m][0];
    }
    __syncthreads();
    const int b = bh >> 3;
    const size_t abase = ((size_t)((b * NTOK + q0) >> 4) * 8 + h) * 512 +
                         (size_t)ks * 2097152;
#pragma unroll
    for (int m = 0; m < 4; ++m) {
        const int row = m * 16 + qi;
        const int sw = row & 7;
        const f16x4 lo = *(const f16x4*)(ts + row * 64 + (((2 * g) ^ sw) << 3));
        const f16x4 hi = *(const f16x4*)(ts + row * 64 + (((2 * g + 1) ^ sw) << 3));
        union { struct { f16x4 lo, hi; } p; f16x8 v; } u;
        u.p.lo = lo; u.p.hi = hi;
        *(f16x8*)(paccF + abase + m * 4096 + lane * 8) = u.v;
    }
}

// ---------------------------------------------------------------------------
// Kernel 3: output projection — pure fragment GEMM, combine fused in-register:
// A-frag = (frag0 + frag1) * (f16)(1/(l0+l1)) — each fragment's 8 elems share
// one (token row, head) so l is a per-lane scalar.  No LDS, no barrier.
// ---------------------------------------------------------------------------
__global__ __launch_bounds__(256) void out_gemm(const _Float16* __restrict__ paccF,
                                                const float* __restrict__ pl,
                                                const _Float16* __restrict__ woutT,
                                                const float* __restrict__ b_out,
                                                float* __restrict__ out) {
    const int wave = threadIdx.x >> 6;
    const int lane = threadIdx.x & 63;
    const int idx16 = lane & 15;
    const int g = lane >> 4;
    const int m_base = blockIdx.x * 64;          // 128 m-blocks
    const int n0 = blockIdx.y * 64 + wave * 16;  // 4 n-blocks * 4 waves
    const int b = m_base >> 11;
    const int nb = m_base & 2047;

    f32x4 acc[4] = {{0.f, 0.f, 0.f, 0.f}, {0.f, 0.f, 0.f, 0.f},
                    {0.f, 0.f, 0.f, 0.f}, {0.f, 0.f, 0.f, 0.f}};

    const _Float16* bp = woutT + (size_t)(blockIdx.y * 4 + wave) * 4096 + lane * 8;
    const _Float16* ap0 = paccF + (size_t)(blockIdx.x * 4) * 4096 + lane * 8;
    const _Float16* ap1 = ap0 + 2097152;

    for (int kt = 0; kt < 8; ++kt) {
        const f16x8 bf = *(const f16x8*)(bp + kt * 512);
        const int plbase = ((b * 8 + kt) * 2) * 2048 + nb;
#pragma unroll
        for (int m = 0; m < 4; ++m) {
            const int n = m * 16 + idx16;
            const float lv = pl[plbase + n] + pl[plbase + 2048 + n];
            const _Float16 hinv = (_Float16)(1.0f / lv);
            const f16x8 a0 = *(const f16x8*)(ap0 + m * 4096 + kt * 512);
            const f16x8 a1 = *(const f16x8*)(ap1 + m * 4096 + kt * 512);
            const f16x8 af = (a0 + a1) * hinv;
            acc[m] = __builtin_amdgcn_mfma_f32_16x16x32_f16(af, bf, acc[m], 0, 0, 0);
        }
    }

    const int c = n0 + idx16;
    const float bias = b_out[c];
#pragma unroll
    for (int m = 0; m < 4; ++m) {
#pragma unroll
        for (int r = 0; r < 4; ++r) {
            const int tok = m_base + m * 16 + g * 4 + r;
            out[tok * 256 + c] = acc[m][r] + bias;
        }
    }
}

extern "C" void kernel_launch(void* const* d_in, const int* in_sizes, int n_in,
                              void* d_out, int out_size, void* d_ws, size_t ws_size,
                              hipStream_t stream) {
    const float* x = (const float*)d_in[0];
    const float* w_qkv = (const float*)d_in[1];
    const float* bias_table = (const float*)d_in[2];
    const float* w_out = (const float*)d_in[3];
    const float* b_out = (const float*)d_in[4];
    // d_in[5] (rel_index) unused: rel = 31*dz + dy + dx + 704, computed inline.
    float* out = (float*)d_out;

    // workspace layout (~22 MB):
    _Float16* paccF = (_Float16*)d_ws;           // 2 parts x 2,097,152 f16
    float* pl = (float*)(paccF + 4194304);       // 131,072 f32
    _Float16* qb = (_Float16*)(pl + 131072);     // 2,097,152 f16 each
    _Float16* kb = qb + 2097152;
    _Float16* vT = kb + 2097152;
    _Float16* wqkvT = vT + 2097152;              // 196,608 f16
    _Float16* woutT = wqkvT + 196608;            // 65,536 f16
    // xh aliases paccF: qkv_gemm (reader) completes before attn writes paccF
    _Float16* xh = (_Float16*)paccF;             // 2,097,152 f16

    prep<<<1280, 256, 0, stream>>>(x, w_qkv, w_out, xh, wqkvT, woutT);
    qkv_gemm<<<dim3(128, 12), 256, 0, stream>>>(xh, wqkvT, qb, kb, vT);
    attn_partial<<<dim3(32, 8, 2), 256, 0, stream>>>(qb, kb, vT, bias_table,
                                                     paccF, pl);
    out_gemm<<<dim3(128, 4), 256, 0, stream>>>(paccF, pl, woutT, b_out, out);
}

// Round 21
// 57.448 us; speedup vs baseline: 1.0510x; 1.0510x over previous
//
#include <hip/hip_runtime.h>
#include <hip/hip_bf16.h>
#include <hip/hip_fp16.h>

#define NTOK 2048
#define HEADS 8
#define DHEAD 32
#define CDIM 256
#define BATCH 4

typedef _Float16 f16x8 __attribute__((ext_vector_type(8)));
typedef _Float16 f16x4 __attribute__((ext_vector_type(4)));
typedef float f32x4 __attribute__((ext_vector_type(4)));
typedef __fp16 fp16v2 __attribute__((ext_vector_type(2)));

static __device__ inline f16x4 pack4(float a, float b, float c, float d) {
    fp16v2 lo = __builtin_amdgcn_cvt_pkrtz(a, b);
    fp16v2 hi = __builtin_amdgcn_cvt_pkrtz(c, d);
    union { struct { fp16v2 lo, hi; } p; f16x4 v; } u;
    u.p.lo = lo; u.p.hi = hi;
    return u.v;
}

static __device__ inline f16x8 pack8f(float a, float b, float c, float d,
                                      float e, float f, float g2, float h2) {
    union { struct { fp16v2 a, b, c, d; } p; f16x8 v; } u;
    u.p.a = __builtin_amdgcn_cvt_pkrtz(a, b);
    u.p.b = __builtin_amdgcn_cvt_pkrtz(c, d);
    u.p.c = __builtin_amdgcn_cvt_pkrtz(e, f);
    u.p.d = __builtin_amdgcn_cvt_pkrtz(g2, h2);
    return u.v;
}

static __device__ inline f16x8 pack8(float4 a, float4 b) {
    return pack8f(a.x, a.y, a.z, a.w, b.x, b.y, b.z, b.w);
}

// ---------------------------------------------------------------------------
// Kernel 0: prep — write ALL GEMM operands in MFMA-FRAGMENT-LINEAR order
// buf[tile][kt][lane][8] so every A/B fragment load downstream is
// base + lane*16B (ideal coalescing, zero address divergence).
// ---------------------------------------------------------------------------
__global__ __launch_bounds__(256) void prep(const float* __restrict__ x,
                                            const float* __restrict__ w_qkv,
                                            const float* __restrict__ w_out,
                                            _Float16* __restrict__ xh,
                                            _Float16* __restrict__ wqkvT,
                                            _Float16* __restrict__ woutT) {
    __shared__ float tl[32][33];
    const int bid = blockIdx.x;
    if (bid < 1024) {
        // x -> xh_frag: 262144 chunks of 8
        const int id = bid * 256 + threadIdx.x;
        const int row = id >> 5;
        const int c = id & 31;
        const int kt = c >> 2;
        const int g = c & 3;
        const float4 a = *(const float4*)(x + row * 256 + kt * 32 + g * 8);
        const float4 b = *(const float4*)(x + row * 256 + kt * 32 + g * 8 + 4);
        const int dst = (row >> 4) * 4096 + kt * 512 + (g * 16 + (row & 15)) * 8;
        *(f16x8*)(xh + dst) = pack8(a, b);
    } else if (bid < 1216) {
        // w_qkv[256k][768n] -> wqkvT_frag, 32x32 tiles: 8 kt x 24 nt
        const int t = bid - 1024;
        const int kt = t / 24, nt = t - kt * 24;
        const int tx = threadIdx.x & 31, ty = threadIdx.x >> 5;
#pragma unroll
        for (int i = 0; i < 4; ++i) {
            const int r = ty + i * 8;
            tl[r][tx] = w_qkv[(kt * 32 + r) * 768 + nt * 32 + tx];
        }
        __syncthreads();
        if (threadIdx.x < 128) {
            const int nl = threadIdx.x & 31;
            const int g2 = threadIdx.x >> 5;
            const int ntile = (nt * 32 + nl) >> 4;
            const int lane = (nl & 15) + 16 * g2;
            const float* col = &tl[g2 * 8][nl];
            *(f16x8*)(wqkvT + (ntile * 8 + kt) * 512 + lane * 8) =
                pack8f(col[0], col[33], col[66], col[99],
                       col[132], col[165], col[198], col[231]);
        }
    } else {
        // w_out[256k][256n] -> woutT_frag, 8 kt x 8 nt
        const int t = bid - 1216;
        const int kt = t >> 3, nt = t & 7;
        const int tx = threadIdx.x & 31, ty = threadIdx.x >> 5;
#pragma unroll
        for (int i = 0; i < 4; ++i) {
            const int r = ty + i * 8;
            tl[r][tx] = w_out[(kt * 32 + r) * 256 + nt * 32 + tx];
        }
        __syncthreads();
        if (threadIdx.x < 128) {
            const int nl = threadIdx.x & 31;
            const int g2 = threadIdx.x >> 5;
            const int ntile = (nt * 32 + nl) >> 4;
            const int lane = (nl & 15) + 16 * g2;
            const float* col = &tl[g2 * 8][nl];
            *(f16x8*)(woutT + (ntile * 8 + kt) * 512 + lane * 8) =
                pack8f(col[0], col[33], col[66], col[99],
                       col[132], col[165], col[198], col[231]);
        }
    }
}

// ---------------------------------------------------------------------------
// Kernel 1: QKV GEMM, fragment-linear operands (1KB/wave contiguous loads).
// vT keys PERMUTED within each 32-key block so attn's S^T registers form a
// valid 16x16x32 B-fragment.
// ---------------------------------------------------------------------------
__global__ __launch_bounds__(256) void qkv_gemm(const _Float16* __restrict__ xh,
                                                const _Float16* __restrict__ wT,
                                                _Float16* __restrict__ qb,
                                                _Float16* __restrict__ kb,
                                                _Float16* __restrict__ vT) {
    __shared__ _Float16 vt_s[64 * 72];  // 64 rows x 72 f16 (144B rows)
    const int wave = threadIdx.x >> 6;
    const int lane = threadIdx.x & 63;
    const int idx16 = lane & 15;
    const int g = lane >> 4;

    const int m_base = blockIdx.x * 64;          // 128 m-blocks
    const int n0 = blockIdx.y * 64 + wave * 16;  // 12 n-blocks * 4 waves

    f32x4 acc[4] = {{0.f, 0.f, 0.f, 0.f}, {0.f, 0.f, 0.f, 0.f},
                    {0.f, 0.f, 0.f, 0.f}, {0.f, 0.f, 0.f, 0.f}};

    const _Float16* bp = wT + (size_t)(blockIdx.y * 4 + wave) * 4096 + lane * 8;
    const _Float16* ap = xh + (size_t)(blockIdx.x * 4) * 4096 + lane * 8;

    for (int kt = 0; kt < 8; ++kt) {
        const f16x8 bf = *(const f16x8*)(bp + kt * 512);
#pragma unroll
        for (int m = 0; m < 4; ++m) {
            const f16x8 af = *(const f16x8*)(ap + m * 4096 + kt * 512);
            acc[m] = __builtin_amdgcn_mfma_f32_16x16x32_f16(af, bf, acc[m], 0, 0, 0);
        }
    }

    const int b = m_base >> 11;
    const int nb = m_base & 2047;
    if (blockIdx.y < 8) {
        const int c = n0 + idx16;
        const int which = c >> 8;
        const int h = (c >> 5) & 7;
        const int d = c & 31;
#pragma unroll
        for (int m = 0; m < 4; ++m) {
#pragma unroll
            for (int r = 0; r < 4; ++r) {
                const int n = nb + m * 16 + g * 4 + r;
                const float val = acc[m][r];
                if (which == 0) {
                    qb[((b * HEADS + h) * NTOK + n) * DHEAD + d] =
                        (_Float16)(val * 0.2550565444545147f);  // d^-.5 * log2e
                } else {
                    kb[((b * HEADS + h) * NTOK + n) * DHEAD + d] = (_Float16)val;
                }
            }
        }
    } else {
        const int cp = wave * 16 + idx16;
#pragma unroll
        for (int m = 0; m < 4; ++m) {
            const int kl = m * 16 + g * 4;  // source key within 64-slab
            const int dst = (kl & 32) + (((kl >> 2) & 3) << 3) +
                            (((kl >> 4) & 1) << 2);
            *(f16x4*)(vt_s + cp * 72 + dst) =
                pack4(acc[m][0], acc[m][1], acc[m][2], acc[m][3]);
        }
        __syncthreads();
        const int cpo = threadIdx.x >> 2;
        const int part = threadIdx.x & 3;
        const int vidx = (blockIdx.y - 8) * 64 + cpo;  // 0..255 = h*32+d
        const int hh = vidx >> 5;
        const int d = vidx & 31;
        const _Float16* src = vt_s + cpo * 72 + part * 16;
        _Float16* dst = vT + ((size_t)(b * HEADS + hh) * DHEAD + d) * NTOK +
                        nb + part * 16;
        *(f16x8*)(dst) = *(const f16x8*)(src);
        *(f16x8*)(dst + 8) = *(const f16x8*)(src + 8);
    }
}

// ---------------------------------------------------------------------------
// Kernel 2: flash attention partials, K-split 2, fixed softmax offset,
// bias folded into QK's C operand (16KB quad table).  K=32 PV (vT permuted),
// LDS-staged K/V double-buffered at 2-tile granularity.  Best measured
// config (57.4 us): 2 blocks/CU TLP sweet spot; all neighbors worse
// (r16 bias-path +1.5, r17 pipelining +1.0, r18 no-split +7.5,
// r20 fused-combine +2.8).
// ---------------------------------------------------------------------------
__global__ __launch_bounds__(256, 4) void attn_partial(
    const _Float16* __restrict__ qp, const _Float16* __restrict__ kp,
    const _Float16* __restrict__ vT, const float* __restrict__ bias_table,
    _Float16* __restrict__ pacc, float* __restrict__ pl) {
    __shared__ float ft[4096];      // quad table: ft[4w+j] = F[w+j]
    __shared__ f16x8 sbuf_v[1024];  // 2 bufs x 8KB (2 tiles x [K 2KB | V 2KB])
    char* sbuf = (char*)sbuf_v;

    const int bh = blockIdx.x;
    const int h = bh & 7;
    for (int u = threadIdx.x; u < 1024; u += 256) {
        const float v =
            bias_table[(1023 - u) * HEADS + h] * 1.4426950408889634f - 8.0f;
        ft[4 * u] = v;
        if (u >= 1) ft[4 * u - 3] = v;
        if (u >= 2) ft[4 * u - 6] = v;
        if (u >= 3) ft[4 * u - 9] = v;
    }

    const int wave = threadIdx.x >> 6;
    const int lane = threadIdx.x & 63;
    const int qi = lane & 15;
    const int g = lane >> 4;
    const int q0 = blockIdx.y * 256 + wave * 64;  // 8 y-blocks, 64 rows/wave
    const int ks = blockIdx.z;
    const int kstart = ks * 1024;

    // ---- staging map: threads 0-127 -> K tile, 128-255 -> V tile ----
    const int tid = threadIdx.x;
    const bool isK = tid < 128;
    const int st_row = (tid & 127) >> 2;
    const int st_c16 = tid & 3;
    const int st_dst = (isK ? 0 : 2048) + st_row * 64 +
                       ((st_c16 ^ ((st_row >> 1) & 3)) << 4);
    const _Float16* st_src = isK
        ? kp + ((size_t)bh * NTOK + kstart + st_row) * DHEAD + st_c16 * 8
        : vT + ((size_t)bh * DHEAD + st_row) * NTOK + kstart + st_c16 * 8;
    const int st_stride = isK ? 32 * DHEAD : 32;  // f16 elems per 32-key tile

    // ---- per-lane LDS read offsets (within a 4KB tile), swizzled ----
    const int swz = (qi >> 1) & 3;
    const int kf0_off = qi * 64 + ((g ^ swz) << 4);
    const int kf1_off = kf0_off + 1024;
    const int va_lo_off = 2048 + qi * 64 + ((g ^ swz) << 4);  // V rows 0-15
    const int va_hi_off = va_lo_off + 1024;                   // V rows 16-31

    // ub[m] = ub0 - m exactly (q0 multiple of 64 -> no nibble wrap, m<4)
    const int ig0 = q0 + qi;
    const int ib0 = 31 * (ig0 >> 8) + ((ig0 >> 4) & 15) + (ig0 & 15) + 704;
    const int ub0 = 1023 - ib0 + 4 * g;

    f16x8 qf[4];
#pragma unroll
    for (int m = 0; m < 4; ++m)
        qf[m] = *(const f16x8*)(qp + (bh * NTOK + q0 + m * 16 + qi) * DHEAD + g * 8);

    f32x4 acc0[4] = {{0.f, 0.f, 0.f, 0.f}, {0.f, 0.f, 0.f, 0.f},
                     {0.f, 0.f, 0.f, 0.f}, {0.f, 0.f, 0.f, 0.f}};
    f32x4 acc1[4] = {{0.f, 0.f, 0.f, 0.f}, {0.f, 0.f, 0.f, 0.f},
                     {0.f, 0.f, 0.f, 0.f}, {0.f, 0.f, 0.f, 0.f}};
    f32x4 accl[4] = {{0.f, 0.f, 0.f, 0.f}, {0.f, 0.f, 0.f, 0.f},
                     {0.f, 0.f, 0.f, 0.f}, {0.f, 0.f, 0.f, 0.f}};
    const f16x8 ones8 = {(_Float16)1.f, (_Float16)1.f, (_Float16)1.f,
                         (_Float16)1.f, (_Float16)1.f, (_Float16)1.f,
                         (_Float16)1.f, (_Float16)1.f};

    // prologue: stage tiles 0,1 into buf 0 (barrier also covers ft fill)
    f16x8 stg0 = *(const f16x8*)(st_src);
    f16x8 stg1 = *(const f16x8*)(st_src + st_stride);
    *(f16x8*)(sbuf + st_dst) = stg0;
    *(f16x8*)(sbuf + 4096 + st_dst) = stg1;
    __syncthreads();

    int cur = 0;
    for (int kt2 = 0; kt2 < 16; ++kt2) {
        // T14: issue next pair's global loads first (hide under compute)
        if (kt2 < 15) {
            stg0 = *(const f16x8*)(st_src + (2 * kt2 + 2) * st_stride);
            stg1 = *(const f16x8*)(st_src + (2 * kt2 + 3) * st_stride);
        }

#pragma unroll
        for (int tp = 0; tp < 2; ++tp) {
            const int kbase = kstart + (kt2 * 2 + tp) * 32;
            const char* bs = sbuf + cur * 8192 + tp * 4096;
            const f16x8 kf0 = *(const f16x8*)(bs + kf0_off);
            const f16x8 kf1 = *(const f16x8*)(bs + kf1_off);
            const f16x8 va_lo = *(const f16x8*)(bs + va_lo_off);
            const f16x8 va_hi = *(const f16x8*)(bs + va_hi_off);

            const int koff = 31 * (kbase >> 8) + ((kbase >> 4) & 15);
            const int u0 = ub0 + koff;

            __builtin_amdgcn_s_setprio(1);
#pragma unroll
            for (int m = 0; m < 4; ++m) {
                const f32x4 c0 = *(const f32x4*)&ft[(u0 - m) << 2];
                const f32x4 c1 = *(const f32x4*)&ft[(u0 - m + 1) << 2];
                f32x4 s0 = __builtin_amdgcn_mfma_f32_16x16x32_f16(kf0, qf[m], c0, 0, 0, 0);
                f32x4 s1 = __builtin_amdgcn_mfma_f32_16x16x32_f16(kf1, qf[m], c1, 0, 0, 0);

                const float p0 = __builtin_amdgcn_exp2f(s0[0]);
                const float p1 = __builtin_amdgcn_exp2f(s0[1]);
                const float p2 = __builtin_amdgcn_exp2f(s0[2]);
                const float p3 = __builtin_amdgcn_exp2f(s0[3]);
                const float p4 = __builtin_amdgcn_exp2f(s1[0]);
                const float p5 = __builtin_amdgcn_exp2f(s1[1]);
                const float p6 = __builtin_amdgcn_exp2f(s1[2]);
                const float p7 = __builtin_amdgcn_exp2f(s1[3]);

                const f16x8 pf = pack8f(p0, p1, p2, p3, p4, p5, p6, p7);

                acc0[m] = __builtin_amdgcn_mfma_f32_16x16x32_f16(va_lo, pf, acc0[m], 0, 0, 0);
                acc1[m] = __builtin_amdgcn_mfma_f32_16x16x32_f16(va_hi, pf, acc1[m], 0, 0, 0);
                accl[m] = __builtin_amdgcn_mfma_f32_16x16x32_f16(ones8, pf, accl[m], 0, 0, 0);
            }
            __builtin_amdgcn_s_setprio(0);
        }

        if (kt2 < 15) {
            *(f16x8*)(sbuf + (cur ^ 1) * 8192 + st_dst) = stg0;
            *(f16x8*)(sbuf + (cur ^ 1) * 8192 + 4096 + st_dst) = stg1;
        }
        __syncthreads();
        cur ^= 1;
    }

    const int part = bh * 2 + ks;
#pragma unroll
    for (int m = 0; m < 4; ++m) {
        const int ig = q0 + m * 16 + qi;
        _Float16* pb = pacc + ((size_t)part * NTOK + ig) * DHEAD;
        *(f16x4*)(pb + g * 4) = pack4(acc0[m][0], acc0[m][1], acc0[m][2], acc0[m][3]);
        *(f16x4*)(pb + 16 + g * 4) = pack4(acc1[m][0], acc1[m][1], acc1[m][2], acc1[m][3]);
        if (g == 0) pl[part * NTOK + ig] = accl[m][0];
    }
}

// ---------------------------------------------------------------------------
// Kernel 3: combine 2 f16 partials into an XOR-swizzled f16 LDS A-tile, then
// MFMA output projection (f32 accumulate).  B operand fragment-linear.
// ---------------------------------------------------------------------------
__global__ __launch_bounds__(256) void out_gemm(const _Float16* __restrict__ pacc,
                                                const float* __restrict__ pl,
                                                const _Float16* __restrict__ woutT,
                                                const float* __restrict__ b_out,
                                                float* __restrict__ out) {
    __shared__ char a_s[64 * 512];  // 64 rows x 256 f16, XOR-swizzled
    const int m_base = blockIdx.x * 64;  // 128 m-blocks

    for (int it = 0; it < 8; ++it) {
        const int chunk = it * 256 + threadIdx.x;
        const int row = chunk >> 5;
        const int c8 = (chunk & 31) * 8;
        const int q = m_base + row;
        const int b = q >> 11;
        const int n = q & 2047;
        const int hh = c8 >> 5;
        const int part0 = (b * 8 + hh) * 2;
        const int doff = c8 & 31;
        const float l = pl[(part0 + 0) * NTOK + n] + pl[(part0 + 1) * NTOK + n];
        const float inv = 1.f / l;
        float s[8] = {0.f, 0.f, 0.f, 0.f, 0.f, 0.f, 0.f, 0.f};
#pragma unroll
        for (int p = 0; p < 2; ++p) {
            const f16x8 v = *(const f16x8*)(pacc +
                ((size_t)(part0 + p) * NTOK + n) * DHEAD + doff);
#pragma unroll
            for (int e = 0; e < 8; ++e) s[e] += (float)v[e];
        }
        float4 ca = {s[0] * inv, s[1] * inv, s[2] * inv, s[3] * inv};
        float4 cb = {s[4] * inv, s[5] * inv, s[6] * inv, s[7] * inv};
        const int baddr = (row * 512 + c8 * 2) ^ ((row & 7) << 4);
        *(f16x8*)(a_s + baddr) = pack8(ca, cb);
    }
    __syncthreads();

    const int wave = threadIdx.x >> 6;
    const int lane = threadIdx.x & 63;
    const int idx16 = lane & 15;
    const int g = lane >> 4;
    const int n0 = blockIdx.y * 64 + wave * 16;  // 4 n-blocks * 4 waves

    f32x4 acc[4] = {{0.f, 0.f, 0.f, 0.f}, {0.f, 0.f, 0.f, 0.f},
                    {0.f, 0.f, 0.f, 0.f}, {0.f, 0.f, 0.f, 0.f}};

    const _Float16* bp = woutT + (size_t)(blockIdx.y * 4 + wave) * 4096 + lane * 8;
    for (int kt = 0; kt < 8; ++kt) {
        const int k0 = kt * 32 + g * 8;
        const f16x8 bf = *(const f16x8*)(bp + kt * 512);
#pragma unroll
        for (int m = 0; m < 4; ++m) {
            const int row = m * 16 + idx16;
            const int baddr = (row * 512 + k0 * 2) ^ ((row & 7) << 4);
            const f16x8 af = *(const f16x8*)(a_s + baddr);
            acc[m] = __builtin_amdgcn_mfma_f32_16x16x32_f16(af, bf, acc[m], 0, 0, 0);
        }
    }

    const int c = n0 + idx16;
    const float bias = b_out[c];
#pragma unroll
    for (int m = 0; m < 4; ++m) {
#pragma unroll
        for (int r = 0; r < 4; ++r) {
            const int tok = m_base + m * 16 + g * 4 + r;
            out[tok * 256 + c] = acc[m][r] + bias;
        }
    }
}

extern "C" void kernel_launch(void* const* d_in, const int* in_sizes, int n_in,
                              void* d_out, int out_size, void* d_ws, size_t ws_size,
                              hipStream_t stream) {
    const float* x = (const float*)d_in[0];
    const float* w_qkv = (const float*)d_in[1];
    const float* bias_table = (const float*)d_in[2];
    const float* w_out = (const float*)d_in[3];
    const float* b_out = (const float*)d_in[4];
    // d_in[5] (rel_index) unused: rel = 31*dz + dy + dx + 704, computed inline.
    float* out = (float*)d_out;

    // workspace layout (~22 MB):
    _Float16* pacc = (_Float16*)d_ws;            // 2*32*2048*32 = 4,194,304 f16
    float* pl = (float*)(pacc + 4194304);        // 131,072 f32
    _Float16* qb = (_Float16*)(pl + 131072);     // 2,097,152 f16 each
    _Float16* kb = qb + 2097152;
    _Float16* vT = kb + 2097152;
    _Float16* wqkvT = vT + 2097152;              // 196,608 f16
    _Float16* woutT = wqkvT + 196608;            // 65,536 f16
    // xh aliases pacc: qkv_gemm (reader) completes before attn writes pacc
    _Float16* xh = (_Float16*)pacc;              // 2,097,152 f16

    prep<<<1280, 256, 0, stream>>>(x, w_qkv, w_out, xh, wqkvT, woutT);
    qkv_gemm<<<dim3(128, 12), 256, 0, stream>>>(xh, wqkvT, qb, kb, vT);
    attn_partial<<<dim3(32, 8, 2), 256, 0, stream>>>(qb, kb, vT, bias_table,
                                                     pacc, pl);
    out_gemm<<<dim3(128, 4), 256, 0, stream>>>(pacc, pl, woutT, b_out, out);
}